// Round 1
// baseline (95.099 us; speedup 1.0000x reference)
//
#include <hip/hip_runtime.h>
#include <stdint.h>

// Problem constants
constexpr int Dn = 10000;
constexpr int Bn = 128;
constexpr int Wn = 512;
constexpr int Hn = 128;
constexpr int BCH = 16;   // b-accumulators per thread in main GEMM

// ---------------------------------------------------------------------------
// Kernel 1: h-reduction.  sT64[w][b] = sum_h x[b][h][w]  (fp64), plus fp32 copy.
// x is (B,H,W) row-major. Thread per (b,w); consecutive threads -> consecutive w
// -> coalesced 256B/wave per h step.
// ---------------------------------------------------------------------------
__global__ __launch_bounds__(256) void reduce_h(const float* __restrict__ x,
                                                double* __restrict__ sT64,
                                                float* __restrict__ sT32) {
    int idx = blockIdx.x * 256 + threadIdx.x;   // 0 .. 65535
    int b = idx >> 9;        // / 512
    int w = idx & (Wn - 1);  // % 512
    const float* p = x + (size_t)b * Hn * Wn + w;
    double a = 0.0;
    #pragma unroll 8
    for (int h = 0; h < Hn; ++h) a += (double)p[(size_t)h * Wn];
    sT64[w * Bn + b] = a;
    sT32[w * Bn + b] = (float)a;
}

// ---------------------------------------------------------------------------
// Kernel 2: pack weight signs into bitmasks.
// bits[g][d], g = 0..15, bit j of word g = (W[g*32+j][d] > 0).
// ---------------------------------------------------------------------------
__global__ __launch_bounds__(256) void pack_w(const float* __restrict__ wts,
                                              uint32_t* __restrict__ bits) {
    int idx = blockIdx.x * 256 + threadIdx.x;   // 0 .. 159999 (+pad)
    if (idx >= 16 * Dn) return;
    int g = idx / Dn;
    int d = idx - g * Dn;
    uint32_t m = 0;
    #pragma unroll
    for (int j = 0; j < 32; ++j)
        m |= (wts[(size_t)(g * 32 + j) * Dn + d] > 0.0f) ? (1u << j) : 0u;
    bits[idx] = m;
}

// ---------------------------------------------------------------------------
// Kernel 3: main "GEMM" in fp32 with bit weights.
// Block: 256 threads over d. Each thread: one d, BCH=16 b-accumulators.
// grid = (ceil(D/256)=40, B/16=8, Ksplit=2).  raw[z][b][d] partial sums.
// sT32 row reads are wave-uniform -> scalar (SGPR) loads.
// Sign applied via one cndmask to +-1.0 per w, then 1 v_fmac per (w,b).
// ---------------------------------------------------------------------------
__global__ __launch_bounds__(256) void gemm_bits(const uint32_t* __restrict__ bits,
                                                 const float* __restrict__ sT32,
                                                 float* __restrict__ raw) {
    int d = blockIdx.x * 256 + threadIdx.x;
    d = d < Dn ? d : Dn - 1;              // clamp: duplicate (identical) work/write
    int b0 = blockIdx.y * BCH;
    int gbase = blockIdx.z * 8;           // 8 mask words = 256 w per z-split

    float acc[BCH];
    #pragma unroll
    for (int i = 0; i < BCH; ++i) acc[i] = 0.0f;

    for (int g = 0; g < 8; ++g) {
        uint32_t m = bits[(size_t)(gbase + g) * Dn + d];
        int wbase = (gbase + g) * 32;
        #pragma unroll
        for (int j = 0; j < 32; ++j) {
            const float* srow = sT32 + (wbase + j) * Bn + b0;  // uniform address
            float sgn = (m & (1u << j)) ? 1.0f : -1.0f;
            #pragma unroll
            for (int i = 0; i < BCH; ++i)
                acc[i] = fmaf(srow[i], sgn, acc[i]);
        }
    }

    float* rp = raw + (size_t)blockIdx.z * ((size_t)Bn * Dn);
    #pragma unroll
    for (int i = 0; i < BCH; ++i)
        rp[(size_t)(b0 + i) * Dn + d] = acc[i];
}

// ---------------------------------------------------------------------------
// Kernel 4: combine K-split partials, emit sign. Outputs with |v| < 0.25
// (worst-case fp32 error bound ~0.06) get an exact fp64 recompute so the
// sign matches a float64 numpy reference bit-for-bit.
// ---------------------------------------------------------------------------
__global__ __launch_bounds__(256) void sign_fix(const float* __restrict__ raw,
                                                const double* __restrict__ sT64,
                                                const float* __restrict__ wts,
                                                float* __restrict__ out) {
    int i = blockIdx.x * 256 + threadIdx.x;
    if (i >= Bn * Dn) return;
    float v = raw[i] + raw[(size_t)Bn * Dn + i];
    float r;
    if (fabsf(v) > 0.25f) {
        r = v > 0.0f ? 1.0f : -1.0f;
    } else {
        int b = i / Dn;
        int d = i - b * Dn;
        double acc = 0.0;
        for (int w = 0; w < Wn; ++w)
            acc = fma((double)wts[(size_t)w * Dn + d], sT64[w * Bn + b], acc);
        r = (acc > 0.0) ? 1.0f : ((acc < 0.0) ? -1.0f : 0.0f);
    }
    out[i] = r;
}

// ---------------------------------------------------------------------------
extern "C" void kernel_launch(void* const* d_in, const int* in_sizes, int n_in,
                              void* d_out, int out_size, void* d_ws, size_t ws_size,
                              hipStream_t stream) {
    const float* x   = (const float*)d_in[0];   // (128,128,512) f32
    const float* wts = (const float*)d_in[1];   // (512,10000)  f32, values +-1
    float* out = (float*)d_out;                 // (128,10000)  f32 signs
    char* ws = (char*)d_ws;

    // workspace layout
    double*   sT64 = (double*)(ws);                 // 512*128*8   = 524288 B
    float*    sT32 = (float*)(ws + 524288);         // 512*128*4   = 262144 B
    uint32_t* bits = (uint32_t*)(ws + 786432);      // 16*10000*4  = 640000 B
    float*    raw  = (float*)(ws + 1426432);        // 2*128*10000*4 = 10240000 B
    // total ~11.7 MB

    reduce_h<<<256, 256, 0, stream>>>(x, sT64, sT32);
    pack_w<<<625, 256, 0, stream>>>(wts, bits);
    gemm_bits<<<dim3(40, 8, 2), 256, 0, stream>>>(bits, sT32, raw);
    sign_fix<<<5000, 256, 0, stream>>>(raw, sT64, wts, out);
}

// Round 2
// 67.389 us; speedup vs baseline: 1.4112x; 1.4112x over previous
//
#include <hip/hip_runtime.h>
#include <stdint.h>

// Problem constants
constexpr int Dn = 10000;
constexpr int Bn = 128;
constexpr int Wn = 512;
constexpr int Hn = 128;
constexpr int BD = Bn * Dn;      // 1,280,000 outputs
constexpr int BCH = 16;          // b-accumulators per thread in main GEMM
constexpr int CAP = 65536;       // ambiguous-list capacity

// ---------------------------------------------------------------------------
// Kernel 1: h-reduction, 4-way h-split for occupancy.
// part[hq][w][b] = sum_{h in hq*32..+32} x[b][h][w]  (fp64)
// 512 blocks x 256 threads; float2 loads (thread owns w-pair).
// Also zeroes the ambiguous counter.
// ---------------------------------------------------------------------------
__global__ __launch_bounds__(256) void reduce_h(const float* __restrict__ x,
                                                double* __restrict__ part,
                                                uint32_t* __restrict__ cnt) {
    if (blockIdx.x == 0 && threadIdx.x == 0) *cnt = 0;
    int tid = blockIdx.x * 256 + threadIdx.x;   // 0 .. 131071
    int hq  = tid >> 15;                        // 0..3
    int rem = tid & 32767;
    int b   = rem >> 8;                         // 0..127
    int wp  = rem & 255;                        // w = 2*wp
    const float2* p = (const float2*)(x + (size_t)b * Hn * Wn + (size_t)(hq * 32) * Wn) + wp;
    double a0 = 0.0, a1 = 0.0;
    #pragma unroll 8
    for (int h = 0; h < 32; ++h) {
        float2 f = p[(size_t)h * (Wn / 2)];
        a0 += (double)f.x;
        a1 += (double)f.y;
    }
    double* pp = part + (size_t)hq * (Wn * Bn);
    pp[(2 * wp)     * Bn + b] = a0;
    pp[(2 * wp + 1) * Bn + b] = a1;
}

// ---------------------------------------------------------------------------
// Kernel 2: combine the 4 h-partials (fixed order) -> sT64 (fp64) + sT32.
// ---------------------------------------------------------------------------
__global__ __launch_bounds__(256) void combine_s(const double* __restrict__ part,
                                                 double* __restrict__ sT64,
                                                 float* __restrict__ sT32) {
    int i = blockIdx.x * 256 + threadIdx.x;     // 0 .. 65535  (= w*128+b)
    double s = ((part[i] + part[65536 + i]) + part[2 * 65536 + i]) + part[3 * 65536 + i];
    sT64[i] = s;
    sT32[i] = (float)s;
}

// ---------------------------------------------------------------------------
// Kernel 3: pack weight signs into bitmasks. bits[g][d] bit j = (W[g*32+j][d] > 0)
// ---------------------------------------------------------------------------
__global__ __launch_bounds__(256) void pack_w(const float* __restrict__ wts,
                                              uint32_t* __restrict__ bits) {
    int idx = blockIdx.x * 256 + threadIdx.x;   // 0 .. 159999 (+pad)
    if (idx >= 16 * Dn) return;
    int g = idx / Dn;
    int d = idx - g * Dn;
    uint32_t m = 0;
    #pragma unroll
    for (int j = 0; j < 32; ++j)
        m |= (wts[(size_t)(g * 32 + j) * Dn + d] > 0.0f) ? (1u << j) : 0u;
    bits[idx] = m;
}

// ---------------------------------------------------------------------------
// Kernel 4: main "GEMM" in fp32 with bit weights. Thread: one d, 16 b-accs.
// grid = (40, 8, 2); raw[z][b][d] partial sums. srow reads are wave-uniform.
// ---------------------------------------------------------------------------
__global__ __launch_bounds__(256) void gemm_bits(const uint32_t* __restrict__ bits,
                                                 const float* __restrict__ sT32,
                                                 float* __restrict__ raw) {
    int d = blockIdx.x * 256 + threadIdx.x;
    d = d < Dn ? d : Dn - 1;              // clamp: duplicate (identical) work/write
    int b0 = blockIdx.y * BCH;
    int gbase = blockIdx.z * 8;           // 8 mask words = 256 w per z-split

    float acc[BCH];
    #pragma unroll
    for (int i = 0; i < BCH; ++i) acc[i] = 0.0f;

    for (int g = 0; g < 8; ++g) {
        uint32_t m = bits[(size_t)(gbase + g) * Dn + d];
        int wbase = (gbase + g) * 32;
        #pragma unroll
        for (int j = 0; j < 32; ++j) {
            const float* srow = sT32 + (wbase + j) * Bn + b0;  // uniform address
            float sgn = (m & (1u << j)) ? 1.0f : -1.0f;
            #pragma unroll
            for (int i = 0; i < BCH; ++i)
                acc[i] = fmaf(srow[i], sgn, acc[i]);
        }
    }

    float* rp = raw + (size_t)blockIdx.z * (size_t)BD;
    #pragma unroll
    for (int i = 0; i < BCH; ++i)
        rp[(size_t)(b0 + i) * Dn + d] = acc[i];
}

// ---------------------------------------------------------------------------
// Kernel 5: combine K-split partials, emit confident signs, compact the
// ambiguous (|v| <= 0.25) indices into a list for exact fixup.
// ---------------------------------------------------------------------------
__global__ __launch_bounds__(256) void combine_sign(const float* __restrict__ raw,
                                                    const uint32_t* __restrict__ bits,
                                                    const double* __restrict__ sT64,
                                                    uint32_t* __restrict__ cnt,
                                                    uint32_t* __restrict__ list,
                                                    float* __restrict__ out) {
    int i = blockIdx.x * 256 + threadIdx.x;
    if (i >= BD) return;
    float v = raw[i] + raw[BD + i];
    if (fabsf(v) > 0.25f) {
        out[i] = v > 0.0f ? 1.0f : -1.0f;
        return;
    }
    uint32_t u = atomicAdd(cnt, 1u);
    if (u < CAP) {
        list[u] = (uint32_t)i;              // fixup_exact writes out[i]
    } else {
        // overflow fallback (effectively never): exact fp64 inline
        int b = i / Dn;
        int d = i - b * Dn;
        double a = 0.0;
        for (int w = 0; w < Wn; ++w) {
            double s = sT64[w * Bn + b];
            a += ((bits[(w >> 5) * Dn + d] >> (w & 31)) & 1u) ? s : -s;
        }
        out[i] = (a > 0.0) ? 1.0f : ((a < 0.0) ? -1.0f : 0.0f);
    }
}

// ---------------------------------------------------------------------------
// Kernel 6: exact fp64 recompute of ambiguous outputs. One WAVE per item:
// 512 terms over 64 lanes (8 each) from packed bits + L2-resident sT64,
// then fp64 butterfly reduce.
// ---------------------------------------------------------------------------
__global__ __launch_bounds__(256) void fixup_exact(const uint32_t* __restrict__ cnt,
                                                   const uint32_t* __restrict__ list,
                                                   const uint32_t* __restrict__ bits,
                                                   const double* __restrict__ sT64,
                                                   float* __restrict__ out) {
    int lane = threadIdx.x & 63;
    int wave = blockIdx.x * 4 + (threadIdx.x >> 6);   // 0..1023
    uint32_t n = *cnt;
    if (n > CAP) n = CAP;
    for (uint32_t item = wave; item < n; item += 1024) {
        int i = (int)list[item];
        int b = i / Dn;
        int d = i - b * Dn;
        double a = 0.0;
        #pragma unroll
        for (int k = 0; k < 8; ++k) {
            int w = lane + 64 * k;
            uint32_t m = bits[(w >> 5) * Dn + d];
            double s = sT64[w * Bn + b];
            a += ((m >> (w & 31)) & 1u) ? s : -s;
        }
        #pragma unroll
        for (int off = 32; off >= 1; off >>= 1)
            a += __shfl_xor(a, off, 64);
        if (lane == 0)
            out[i] = (a > 0.0) ? 1.0f : ((a < 0.0) ? -1.0f : 0.0f);
    }
}

// ---------------------------------------------------------------------------
extern "C" void kernel_launch(void* const* d_in, const int* in_sizes, int n_in,
                              void* d_out, int out_size, void* d_ws, size_t ws_size,
                              hipStream_t stream) {
    const float* x   = (const float*)d_in[0];   // (128,128,512) f32
    const float* wts = (const float*)d_in[1];   // (512,10000)  f32, values +-1
    float* out = (float*)d_out;                 // (128,10000)  f32 signs
    char* ws = (char*)d_ws;

    // workspace layout (part64 overlays raw: disjoint lifetimes)
    double*   part = (double*)(ws);                   // 4*512*128*8 = 2 MB (dead after combine_s)
    float*    raw  = (float*)(ws);                    // 2*1,280,000*4 = 10,240,000 B
    double*   sT64 = (double*)(ws + 10240000);        // 524,288 B
    float*    sT32 = (float*)(ws + 10764288);         // 262,144 B
    uint32_t* bits = (uint32_t*)(ws + 11026432);      // 640,000 B
    uint32_t* cnt  = (uint32_t*)(ws + 11666432);      // 256 B (padded)
    uint32_t* list = (uint32_t*)(ws + 11666688);      // 262,144 B
    // total ~11.93 MB

    reduce_h<<<512, 256, 0, stream>>>(x, part, cnt);
    combine_s<<<256, 256, 0, stream>>>(part, sT64, sT32);
    pack_w<<<625, 256, 0, stream>>>(wts, bits);
    gemm_bits<<<dim3(40, 8, 2), 256, 0, stream>>>(bits, sT32, raw);
    combine_sign<<<5000, 256, 0, stream>>>(raw, bits, sT64, cnt, list, out);
    fixup_exact<<<256, 256, 0, stream>>>(cnt, list, bits, sT64, out);
}